// Round 4
// baseline (378.847 us; speedup 1.0000x reference)
//
#include <hip/hip_runtime.h>

#define B_N 32
#define S_N 1024

typedef __attribute__((ext_vector_type(8))) short sh8;
typedef __attribute__((ext_vector_type(4))) short sh4;
typedef __attribute__((ext_vector_type(4))) float f4;

__device__ __forceinline__ short f2bf(float f) {
  unsigned u = __builtin_bit_cast(unsigned, f);
  u += 0x7fff + ((u >> 16) & 1);
  return (short)(u >> 16);
}
__device__ __forceinline__ float dot4(f4 a, f4 w) {
  return a.x * w.x + a.y * w.y + a.z * w.z + a.w * w.w;
}

// ---------- Phase 1a: QK projections, register-tiled 64x64 ----------
template <int DIN>
__global__ __launch_bounds__(256) void proj_qk2(
    const float* __restrict__ in, const float* __restrict__ W,
    const float* __restrict__ bias, short* __restrict__ out) {
  constexpr int NS = DIN / 4;
  __shared__ f4 w_lds[64][NS + 1];
  __shared__ f4 a_lds[64][NS + 1];
  const int tid = threadIdx.x;
  for (int e = tid; e < 64 * NS; e += 256) w_lds[e / NS][e % NS] = ((const f4*)W)[e];
  const f4* inb = (const f4*)(in + (size_t)blockIdx.x * 64 * DIN);
  for (int e = tid; e < 64 * NS; e += 256) a_lds[e / NS][e % NS] = inb[e];
  __syncthreads();
  const int c1 = tid & 15, r4 = tid >> 4;
  float acc[4][4];
#pragma unroll
  for (int i = 0; i < 4; ++i)
#pragma unroll
    for (int k = 0; k < 4; ++k) acc[i][k] = 0.f;
#pragma unroll
  for (int d = 0; d < NS; ++d) {
    f4 w[4], a[4];
#pragma unroll
    for (int k = 0; k < 4; ++k) w[k] = w_lds[c1 + k * 16][d];
#pragma unroll
    for (int i = 0; i < 4; ++i) a[i] = a_lds[r4 * 4 + i][d];
#pragma unroll
    for (int i = 0; i < 4; ++i)
#pragma unroll
      for (int k = 0; k < 4; ++k) acc[i][k] += dot4(a[i], w[k]);
  }
  const size_t r0 = (size_t)blockIdx.x * 64;
#pragma unroll
  for (int i = 0; i < 4; ++i)
#pragma unroll
    for (int k = 0; k < 4; ++k)
      out[(r0 + r4 * 4 + i) * 64 + c1 + k * 16] = f2bf(acc[i][k] + bias[c1 + k * 16]);
}

// ---------- Phase 1b: V projection half (64 cols), transposed store ----------
__global__ __launch_bounds__(256) void proj_v2(
    const float* __restrict__ in, const float* __restrict__ W,
    const float* __restrict__ bias, short* __restrict__ vt) {
  constexpr int NS = 32;
  __shared__ f4 w_lds[64][NS + 1];
  __shared__ f4 a_lds[64][NS + 1];
  __shared__ short tile[64][72];
  const int tid = threadIdx.x;
  for (int e = tid; e < 64 * NS; e += 256) w_lds[e >> 5][e & 31] = ((const f4*)W)[e];
  const f4* inb = (const f4*)(in + (size_t)blockIdx.x * 64 * 128);
  for (int e = tid; e < 64 * NS; e += 256) a_lds[e >> 5][e & 31] = inb[e];
  __syncthreads();
  const int c1 = tid & 15, r4 = tid >> 4;
  float acc[4][4];
#pragma unroll
  for (int i = 0; i < 4; ++i)
#pragma unroll
    for (int k = 0; k < 4; ++k) acc[i][k] = 0.f;
#pragma unroll
  for (int d = 0; d < NS; ++d) {
    f4 w[4], a[4];
#pragma unroll
    for (int k = 0; k < 4; ++k) w[k] = w_lds[c1 + k * 16][d];
#pragma unroll
    for (int i = 0; i < 4; ++i) a[i] = a_lds[r4 * 4 + i][d];
#pragma unroll
    for (int i = 0; i < 4; ++i)
#pragma unroll
      for (int k = 0; k < 4; ++k) acc[i][k] += dot4(a[i], w[k]);
  }
#pragma unroll
  for (int i = 0; i < 4; ++i)
#pragma unroll
    for (int k = 0; k < 4; ++k)
      tile[c1 + k * 16][r4 * 4 + i] = f2bf(acc[i][k] + bias[c1 + k * 16]);
  __syncthreads();
  const int b = (blockIdx.x * 64) / S_N, s0 = (blockIdx.x * 64) % S_N;
  const int j = tid >> 2, seg = tid & 3;
  sh8 v0 = *(sh8*)&tile[j][seg * 16];
  sh8 v1 = *(sh8*)&tile[j][seg * 16 + 8];
  short* dst = vt + ((size_t)(b * 128 + j)) * S_N + s0 + seg * 16;
  *(sh8*)dst = v0;
  *(sh8*)(dst + 8) = v1;
}

// masks: sign(sum |row|) for queries_it and keys_it (rows of 128)
__global__ void mask_kernel(const float* __restrict__ q, const float* __restrict__ k,
                            float* __restrict__ qm, float* __restrict__ km, int N) {
  int r = blockIdx.x * blockDim.x + threadIdx.x;
  if (r >= N) return;
  float sq = 0.f, sk = 0.f;
  const f4* qp = (const f4*)(q + (size_t)r * 128);
  const f4* kp = (const f4*)(k + (size_t)r * 128);
#pragma unroll
  for (int d = 0; d < 32; ++d) {
    f4 a = qp[d];
    sq += fabsf(a.x) + fabsf(a.y) + fabsf(a.z) + fabsf(a.w);
    f4 b = kp[d];
    sk += fabsf(b.x) + fabsf(b.y) + fabsf(b.z) + fabsf(b.w);
  }
  qm[r] = (sq != 0.f) ? 1.f : 0.f;
  km[r] = (sk != 0.f) ? 1.f : 0.f;
}

// ---------- Phase 2: fused dual-channel attention, K-split, swapped QK^T ----------
// Grid: 2048 blocks (XCD-swizzled), 4 waves; block = 16 q-rows, wave = 256 keys.
// Swapped QK^T: mfma(K_frag, Q_frag) -> C = S^T with k=grp*4+r, q=col. Each
// lane's 4 scores line up with ONE contiguous f4 of noise and kmask -> MLP+exp
// run straight off the MFMA output in f32 registers (no score exchange, no
// bulk preload, no spills). P packed bf16 -> LDS in PV A-fragment layout.
// Logits ~1e-3 by construction => fixed softmax max 0 is safe.
__global__ __launch_bounds__(256, 4) void attn_kernel(
    const short* __restrict__ qit, const short* __restrict__ kit,
    const short* __restrict__ qctx, const short* __restrict__ kctx,
    const short* __restrict__ vt,     // [B,128,S] bf16
    const float* __restrict__ noise,  // [B,2,S,S]
    const float* __restrict__ sigma,  // [B,2]
    const float* __restrict__ qmask, const float* __restrict__ kmask,  // [B,S]
    const float* __restrict__ qin,    // queries_it [B,S,128]
    const float* __restrict__ W1, const float* __restrict__ b1,
    const float* __restrict__ W2, const float* __restrict__ b2,
    float* __restrict__ out) {
  // per-wave 8704 B: P tiles [2][16][72] bf16 (4608 B), later O-partial [16][136] f32
  __shared__ __align__(16) char lds_raw[4][8704];
  __shared__ float lsum_lds[4][2][16];

  const int tid = threadIdx.x;
  const int wave = tid >> 6, lane = tid & 63;
  const int bid = blockIdx.x;
  const int wg = ((bid & 7) << 8) | (bid >> 3);  // XCD swizzle (2048 % 8 == 0)
  const int b = wg >> 6, qt = wg & 63;
  const int qbase = qt * 16;
  const int col = lane & 15, grp = lane >> 4;
  const int kw = wave * 256;

  const float w100 = W1[0], w101 = W1[1], w110 = W1[2], w111 = W1[3];
  const float bb10 = b1[0], bb11 = b1[1];
  const float sc = 0.125f;
  const float w200 = W2[0] * sc, w201 = W2[1] * sc, w210 = W2[2] * sc, w211 = W2[3] * sc;
  const float bb20 = b2[0] * sc, bb21 = b2[1] * sc;
  float sg0 = sigma[b * 2 + 0]; sg0 *= sg0;
  float sg1 = sigma[b * 2 + 1]; sg1 *= sg1;

  // Q fragments (B-operand: B[k=d][col=q], d = grp*8 + t*32 + e)
  const int qrow = qbase + col;
  sh8 aqit[2], aqctx[2];
#pragma unroll
  for (int t = 0; t < 2; ++t) {
    aqit[t] = *(const sh8*)(qit + ((size_t)(b * S_N + qrow)) * 64 + grp * 8 + t * 32);
    aqctx[t] = *(const sh8*)(qctx + ((size_t)(b * S_N + qrow)) * 64 + grp * 8 + t * 32);
  }

  f4 acc[2][4];
#pragma unroll
  for (int h = 0; h < 2; ++h)
#pragma unroll
    for (int dt = 0; dt < 4; ++dt) acc[h][dt] = (f4)0.f;
  float rs0 = 0.f, rs1 = 0.f;  // partial sum-exp for q = col

  const float* noise0 = noise + (size_t)(b * 2) * S_N * S_N + (size_t)qrow * S_N + grp * 4;
  const float* noise1 = noise0 + (size_t)S_N * S_N;
  const float* kmb = kmask + b * S_N + grp * 4;
  short* pw = (short*)lds_raw[wave];  // [2][16][72]

  for (int kc = kw; kc < kw + 256; kc += 64) {
    // --- QK^T (swapped): all 16 MFMAs issued back-to-back
    f4 sit[4], sctx[4];
#pragma unroll
    for (int kt = 0; kt < 4; ++kt) {
      const int krow = kc + kt * 16 + col;
      sit[kt] = (f4)0.f;
      sctx[kt] = (f4)0.f;
#pragma unroll
      for (int t = 0; t < 2; ++t) {
        sh8 bk = *(const sh8*)(kit + ((size_t)(b * S_N + krow)) * 64 + grp * 8 + t * 32);
        sit[kt] = __builtin_amdgcn_mfma_f32_16x16x32_bf16(bk, aqit[t], sit[kt], 0, 0, 0);
        sh8 bc = *(const sh8*)(kctx + ((size_t)(b * S_N + krow)) * 64 + grp * 8 + t * 32);
        sctx[kt] = __builtin_amdgcn_mfma_f32_16x16x32_bf16(bc, aqctx[t], sctx[kt], 0, 0, 0);
      }
    }
    // --- MLP + exp + mask per kt (scores stay in f32 regs; noise is one f4)
#pragma unroll
    for (int kt = 0; kt < 4; ++kt) {
      f4 n0 = *(const f4*)(noise0 + kc + kt * 16);
      f4 n1 = *(const f4*)(noise1 + kc + kt * 16);
      f4 km = *(const f4*)(kmb + kc + kt * 16);
      sh4 po, pc;
#pragma unroll
      for (int r = 0; r < 4; ++r) {
        float x0 = fmaf(n0[r], sg0, sit[kt][r]);
        float x1 = fmaf(n1[r], sg1, sctx[kt][r]);
        float h0 = fmaxf(fmaf(w101, x1, fmaf(w100, x0, bb10)), 0.f);
        float h1 = fmaxf(fmaf(w111, x1, fmaf(w110, x0, bb11)), 0.f);
        float L0 = fmaf(w201, h1, fmaf(w200, h0, bb20));
        float L1 = fmaf(w211, h1, fmaf(w210, h0, bb21));
        float p0 = __expf(L0) * km[r];
        float p1 = __expf(L1) * km[r];
        rs0 += p0;
        rs1 += p1;
        po[r] = f2bf(p0);
        pc[r] = f2bf(p1);
      }
      *(sh4*)&pw[0 * 1152 + col * 72 + kt * 16 + grp * 4] = po;
      *(sh4*)&pw[1 * 1152 + col * 72 + kt * 16 + grp * 4] = pc;
    }
    // --- PV (A = P from LDS, row=lane&15=q; B = V^T fragments from global)
#pragma unroll
    for (int h = 0; h < 2; ++h) {
      sh8 pa[2];
#pragma unroll
      for (int t = 0; t < 2; ++t)
        pa[t] = *(const sh8*)&pw[h * 1152 + col * 72 + grp * 8 + t * 32];
#pragma unroll
      for (int dt = 0; dt < 4; ++dt) {
        const int drow = h * 64 + dt * 16 + col;
#pragma unroll
        for (int t = 0; t < 2; ++t) {
          sh8 bv = *(const sh8*)(vt + ((size_t)b * 128 + drow) * S_N + kc + grp * 8 + t * 32);
          acc[h][dt] = __builtin_amdgcn_mfma_f32_16x16x32_bf16(pa[t], bv, acc[h][dt], 0, 0, 0);
        }
      }
    }
  }

  // reduce sum-exp across the 4 lanes sharing q-col, stash per-wave
  rs0 += __shfl_xor(rs0, 16); rs0 += __shfl_xor(rs0, 32);
  rs1 += __shfl_xor(rs1, 16); rs1 += __shfl_xor(rs1, 32);
  if (lane < 16) {
    lsum_lds[wave][0][col] = rs0;
    lsum_lds[wave][1][col] = rs1;
  }
  // partial O -> per-wave LDS region [16][136] f32 (overlays P region)
  float* obuf = (float*)lds_raw[wave];
#pragma unroll
  for (int h = 0; h < 2; ++h)
#pragma unroll
    for (int dt = 0; dt < 4; ++dt)
#pragma unroll
      for (int r = 0; r < 4; ++r)
        obuf[(grp * 4 + r) * 136 + h * 64 + dt * 16 + col] = acc[h][dt][r];
  __syncthreads();

  // epilogue: 256 threads cover 16 rows x 128 dims
  const int orow = tid >> 4, d0 = (tid & 15) * 8;
  const float qm = qmask[(size_t)b * S_N + qbase + orow];
  float ls0 = lsum_lds[0][0][orow] + lsum_lds[1][0][orow] + lsum_lds[2][0][orow] + lsum_lds[3][0][orow];
  float ls1 = lsum_lds[0][1][orow] + lsum_lds[1][1][orow] + lsum_lds[2][1][orow] + lsum_lds[3][1][orow];
  f4 s0v = (f4)0.f, s1v = (f4)0.f;
#pragma unroll
  for (int w = 0; w < 4; ++w) {
    const float* ob = (const float*)lds_raw[w];
    s0v += *(const f4*)&ob[orow * 136 + d0];
    s1v += *(const f4*)&ob[orow * 136 + d0 + 4];
  }
  const float sc2 = qm / ((d0 >= 64) ? ls1 : ls0);
  const size_t o = ((size_t)(b * S_N + qbase + orow)) * 128 + d0;
  f4 q0 = *(const f4*)(qin + o), q1 = *(const f4*)(qin + o + 4);
  f4 r0v, r1v;
#pragma unroll
  for (int i = 0; i < 4; ++i) {
    r0v[i] = s0v[i] * sc2 + q0[i];
    r1v[i] = s1v[i] * sc2 + q1[i];
  }
  *(f4*)(out + o) = r0v;
  *(f4*)(out + o + 4) = r1v;
}

extern "C" void kernel_launch(void* const* d_in, const int* in_sizes, int n_in,
                              void* d_out, int out_size, void* d_ws, size_t ws_size,
                              hipStream_t stream) {
  const float* queries_it = (const float*)d_in[0];
  const float* queries_ctx = (const float*)d_in[1];
  const float* keys_it = (const float*)d_in[2];
  const float* keys_ctx = (const float*)d_in[3];
  const float* sigma = (const float*)d_in[4];
  const float* noise = (const float*)d_in[5];
  const float* Wq_it = (const float*)d_in[6];
  const float* bq_it = (const float*)d_in[7];
  const float* Wk_it = (const float*)d_in[8];
  const float* bk_it = (const float*)d_in[9];
  const float* Wq_ctx = (const float*)d_in[10];
  const float* bq_ctx = (const float*)d_in[11];
  const float* Wk_ctx = (const float*)d_in[12];
  const float* bk_ctx = (const float*)d_in[13];
  const float* Wv = (const float*)d_in[14];
  const float* bv = (const float*)d_in[15];
  const float* W1 = (const float*)d_in[16];
  const float* b1 = (const float*)d_in[17];
  const float* W2 = (const float*)d_in[18];
  const float* b2 = (const float*)d_in[19];
  float* out = (float*)d_out;

  char* ws = (char*)d_ws;
  short* qit = (short*)(ws);                    // 4 MB
  short* kit = (short*)(ws + (4ull << 20));     // 4 MB
  short* qctx = (short*)(ws + (8ull << 20));    // 4 MB
  short* kctx = (short*)(ws + (12ull << 20));   // 4 MB
  short* vt = (short*)(ws + (16ull << 20));     // 8 MB  [B,128,S]
  float* qmask = (float*)(ws + (24ull << 20));  // 128 KB
  float* kmask = (float*)(ws + (24ull << 20) + (size_t)B_N * S_N * 4);

  const int NR = B_N * S_N;
  proj_qk2<128><<<dim3(NR / 64), 256, 0, stream>>>(queries_it, Wq_it, bq_it, qit);
  proj_qk2<128><<<dim3(NR / 64), 256, 0, stream>>>(keys_it, Wk_it, bk_it, kit);
  proj_qk2<64><<<dim3(NR / 64), 256, 0, stream>>>(queries_ctx, Wq_ctx, bq_ctx, qctx);
  proj_qk2<64><<<dim3(NR / 64), 256, 0, stream>>>(keys_ctx, Wk_ctx, bk_ctx, kctx);
  proj_v2<<<dim3(NR / 64), 256, 0, stream>>>(keys_it, Wv, bv, vt);
  proj_v2<<<dim3(NR / 64), 256, 0, stream>>>(keys_it, Wv + 64 * 128, bv + 64, vt + 64ull * S_N);
  mask_kernel<<<dim3(NR / 256), 256, 0, stream>>>(queries_it, keys_it, qmask, kmask, NR);

  attn_kernel<<<dim3(B_N * (S_N / 16)), 256, 0, stream>>>(
      qit, kit, qctx, kctx, vt, noise, sigma, qmask, kmask, queries_it,
      W1, b1, W2, b2, out);
}

// Round 5
// 272.067 us; speedup vs baseline: 1.3925x; 1.3925x over previous
//
#include <hip/hip_runtime.h>

#define B_N 32
#define S_N 1024

typedef __attribute__((ext_vector_type(8))) short sh8;
typedef __attribute__((ext_vector_type(4))) short sh4;
typedef __attribute__((ext_vector_type(4))) float f4;

__device__ __forceinline__ short f2bf(float f) {
  unsigned u = __builtin_bit_cast(unsigned, f);
  u += 0x7fff + ((u >> 16) & 1);
  return (short)(u >> 16);
}
__device__ __forceinline__ float dot4(f4 a, f4 w) {
  return a.x * w.x + a.y * w.y + a.z * w.z + a.w * w.w;
}

// ---------- Phase 1a: QK projections, register-tiled 64x64 ----------
template <int DIN>
__global__ __launch_bounds__(256) void proj_qk2(
    const float* __restrict__ in, const float* __restrict__ W,
    const float* __restrict__ bias, short* __restrict__ out) {
  constexpr int NS = DIN / 4;
  __shared__ f4 w_lds[64][NS + 1];
  __shared__ f4 a_lds[64][NS + 1];
  const int tid = threadIdx.x;
  for (int e = tid; e < 64 * NS; e += 256) w_lds[e / NS][e % NS] = ((const f4*)W)[e];
  const f4* inb = (const f4*)(in + (size_t)blockIdx.x * 64 * DIN);
  for (int e = tid; e < 64 * NS; e += 256) a_lds[e / NS][e % NS] = inb[e];
  __syncthreads();
  const int c1 = tid & 15, r4 = tid >> 4;
  float acc[4][4];
#pragma unroll
  for (int i = 0; i < 4; ++i)
#pragma unroll
    for (int k = 0; k < 4; ++k) acc[i][k] = 0.f;
#pragma unroll
  for (int d = 0; d < NS; ++d) {
    f4 w[4], a[4];
#pragma unroll
    for (int k = 0; k < 4; ++k) w[k] = w_lds[c1 + k * 16][d];
#pragma unroll
    for (int i = 0; i < 4; ++i) a[i] = a_lds[r4 * 4 + i][d];
#pragma unroll
    for (int i = 0; i < 4; ++i)
#pragma unroll
      for (int k = 0; k < 4; ++k) acc[i][k] += dot4(a[i], w[k]);
  }
  const size_t r0 = (size_t)blockIdx.x * 64;
#pragma unroll
  for (int i = 0; i < 4; ++i)
#pragma unroll
    for (int k = 0; k < 4; ++k)
      out[(r0 + r4 * 4 + i) * 64 + c1 + k * 16] = f2bf(acc[i][k] + bias[c1 + k * 16]);
}

// ---------- Phase 1b: V projection half (64 cols), transposed store ----------
__global__ __launch_bounds__(256) void proj_v2(
    const float* __restrict__ in, const float* __restrict__ W,
    const float* __restrict__ bias, short* __restrict__ vt) {
  constexpr int NS = 32;
  __shared__ f4 w_lds[64][NS + 1];
  __shared__ f4 a_lds[64][NS + 1];
  __shared__ short tile[64][72];
  const int tid = threadIdx.x;
  for (int e = tid; e < 64 * NS; e += 256) w_lds[e >> 5][e & 31] = ((const f4*)W)[e];
  const f4* inb = (const f4*)(in + (size_t)blockIdx.x * 64 * 128);
  for (int e = tid; e < 64 * NS; e += 256) a_lds[e >> 5][e & 31] = inb[e];
  __syncthreads();
  const int c1 = tid & 15, r4 = tid >> 4;
  float acc[4][4];
#pragma unroll
  for (int i = 0; i < 4; ++i)
#pragma unroll
    for (int k = 0; k < 4; ++k) acc[i][k] = 0.f;
#pragma unroll
  for (int d = 0; d < NS; ++d) {
    f4 w[4], a[4];
#pragma unroll
    for (int k = 0; k < 4; ++k) w[k] = w_lds[c1 + k * 16][d];
#pragma unroll
    for (int i = 0; i < 4; ++i) a[i] = a_lds[r4 * 4 + i][d];
#pragma unroll
    for (int i = 0; i < 4; ++i)
#pragma unroll
      for (int k = 0; k < 4; ++k) acc[i][k] += dot4(a[i], w[k]);
  }
#pragma unroll
  for (int i = 0; i < 4; ++i)
#pragma unroll
    for (int k = 0; k < 4; ++k)
      tile[c1 + k * 16][r4 * 4 + i] = f2bf(acc[i][k] + bias[c1 + k * 16]);
  __syncthreads();
  const int b = (blockIdx.x * 64) / S_N, s0 = (blockIdx.x * 64) % S_N;
  const int j = tid >> 2, seg = tid & 3;
  sh8 v0 = *(sh8*)&tile[j][seg * 16];
  sh8 v1 = *(sh8*)&tile[j][seg * 16 + 8];
  short* dst = vt + ((size_t)(b * 128 + j)) * S_N + s0 + seg * 16;
  *(sh8*)dst = v0;
  *(sh8*)(dst + 8) = v1;
}

// masks: sign(sum |row|) for queries_it and keys_it (rows of 128)
__global__ void mask_kernel(const float* __restrict__ q, const float* __restrict__ k,
                            float* __restrict__ qm, float* __restrict__ km, int N) {
  int r = blockIdx.x * blockDim.x + threadIdx.x;
  if (r >= N) return;
  float sq = 0.f, sk = 0.f;
  const f4* qp = (const f4*)(q + (size_t)r * 128);
  const f4* kp = (const f4*)(k + (size_t)r * 128);
#pragma unroll
  for (int d = 0; d < 32; ++d) {
    f4 a = qp[d];
    sq += fabsf(a.x) + fabsf(a.y) + fabsf(a.z) + fabsf(a.w);
    f4 b = kp[d];
    sk += fabsf(b.x) + fabsf(b.y) + fabsf(b.z) + fabsf(b.w);
  }
  qm[r] = (sq != 0.f) ? 1.f : 0.f;
  km[r] = (sk != 0.f) ? 1.f : 0.f;
}

// ---------- Phase 2: fused dual-channel attention ----------
// Grid: 2048 blocks (XCD-swizzled), 4 waves; block = 16 q-rows, wave = 256 keys.
// Swapped QK^T: mfma(K,Q) -> C = S^T, k=grp*4+r, q=col; each lane's 4 scores
// need exactly one f4 of noise/kmask. Chunk of 64 keys processed as two
// 32-key halves (PV A-fragment t-slice th needs only keys th*32..th*32+32):
//   {noise issue, 8 QK MFMAs, MLP+exp, P->LDS, 8 PV MFMAs}
// keeps sit/sctx at 2 f4 live (no spills under 168-reg budget).
// Logits ~1e-3 by construction => fixed softmax max 0 is safe.
__global__ __launch_bounds__(256, 3) void attn_kernel(
    const short* __restrict__ qit, const short* __restrict__ kit,
    const short* __restrict__ qctx, const short* __restrict__ kctx,
    const short* __restrict__ vt,     // [B,128,S] bf16
    const float* __restrict__ noise,  // [B,2,S,S]
    const float* __restrict__ sigma,  // [B,2]
    const float* __restrict__ qmask, const float* __restrict__ kmask,  // [B,S]
    const float* __restrict__ qin,    // queries_it [B,S,128]
    const float* __restrict__ W1, const float* __restrict__ b1,
    const float* __restrict__ W2, const float* __restrict__ b2,
    float* __restrict__ out) {
  // per-wave 8704 B: P tiles [2][16][72] bf16, later O-partial [16][136] f32
  __shared__ __align__(16) char lds_raw[4][8704];
  __shared__ float lsum_lds[4][2][16];

  const int tid = threadIdx.x;
  const int wave = tid >> 6, lane = tid & 63;
  const int bid = blockIdx.x;
  const int wg = ((bid & 7) << 8) | (bid >> 3);  // XCD swizzle (2048 % 8 == 0)
  const int b = wg >> 6, qt = wg & 63;
  const int qbase = qt * 16;
  const int col = lane & 15, grp = lane >> 4;
  const int kw = wave * 256;

  const float w100 = W1[0], w101 = W1[1], w110 = W1[2], w111 = W1[3];
  const float bb10 = b1[0], bb11 = b1[1];
  const float sc = 0.125f;
  const float w200 = W2[0] * sc, w201 = W2[1] * sc, w210 = W2[2] * sc, w211 = W2[3] * sc;
  const float bb20 = b2[0] * sc, bb21 = b2[1] * sc;
  float sg0 = sigma[b * 2 + 0]; sg0 *= sg0;
  float sg1 = sigma[b * 2 + 1]; sg1 *= sg1;

  // Q fragments (B-operand: B[k=d][col=q], d = grp*8 + t*32 + e)
  const int qrow = qbase + col;
  sh8 aqit[2], aqctx[2];
#pragma unroll
  for (int t = 0; t < 2; ++t) {
    aqit[t] = *(const sh8*)(qit + ((size_t)(b * S_N + qrow)) * 64 + grp * 8 + t * 32);
    aqctx[t] = *(const sh8*)(qctx + ((size_t)(b * S_N + qrow)) * 64 + grp * 8 + t * 32);
  }

  f4 acc[2][4];
#pragma unroll
  for (int h = 0; h < 2; ++h)
#pragma unroll
    for (int dt = 0; dt < 4; ++dt) acc[h][dt] = (f4)0.f;
  float rs0 = 0.f, rs1 = 0.f;  // partial sum-exp for q = col

  const float* noise0 = noise + (size_t)(b * 2) * S_N * S_N + (size_t)qrow * S_N + grp * 4;
  const float* noise1 = noise0 + (size_t)S_N * S_N;
  const float* kmb = kmask + b * S_N + grp * 4;
  short* pw = (short*)lds_raw[wave];  // [2][16][72]

  for (int kc = kw; kc < kw + 256; kc += 64) {
#pragma unroll
    for (int th = 0; th < 2; ++th) {  // 32-key half
      const int k0 = kc + th * 32;
      // noise + mask for this half (issued before the MFMAs)
      f4 n0[2], n1[2], km[2];
#pragma unroll
      for (int kt = 0; kt < 2; ++kt) {
        n0[kt] = *(const f4*)(noise0 + k0 + kt * 16);
        n1[kt] = *(const f4*)(noise1 + k0 + kt * 16);
        km[kt] = *(const f4*)(kmb + k0 + kt * 16);
      }
      // QK^T (swapped) for 2 key-tiles
      f4 sit[2], sctx[2];
#pragma unroll
      for (int kt = 0; kt < 2; ++kt) {
        const int krow = k0 + kt * 16 + col;
        sit[kt] = (f4)0.f;
        sctx[kt] = (f4)0.f;
#pragma unroll
        for (int t = 0; t < 2; ++t) {
          sh8 bk = *(const sh8*)(kit + ((size_t)(b * S_N + krow)) * 64 + grp * 8 + t * 32);
          sit[kt] = __builtin_amdgcn_mfma_f32_16x16x32_bf16(bk, aqit[t], sit[kt], 0, 0, 0);
          sh8 bc = *(const sh8*)(kctx + ((size_t)(b * S_N + krow)) * 64 + grp * 8 + t * 32);
          sctx[kt] = __builtin_amdgcn_mfma_f32_16x16x32_bf16(bc, aqctx[t], sctx[kt], 0, 0, 0);
        }
      }
      // MLP + exp + mask; P -> LDS (PV A layout)
#pragma unroll
      for (int kt = 0; kt < 2; ++kt) {
        sh4 po, pc;
#pragma unroll
        for (int r = 0; r < 4; ++r) {
          float x0 = fmaf(n0[kt][r], sg0, sit[kt][r]);
          float x1 = fmaf(n1[kt][r], sg1, sctx[kt][r]);
          float h0 = fmaxf(fmaf(w101, x1, fmaf(w100, x0, bb10)), 0.f);
          float h1 = fmaxf(fmaf(w111, x1, fmaf(w110, x0, bb11)), 0.f);
          float L0 = fmaf(w201, h1, fmaf(w200, h0, bb20));
          float L1 = fmaf(w211, h1, fmaf(w210, h0, bb21));
          float p0 = __expf(L0) * km[kt][r];
          float p1 = __expf(L1) * km[kt][r];
          rs0 += p0;
          rs1 += p1;
          po[r] = f2bf(p0);
          pc[r] = f2bf(p1);
        }
        *(sh4*)&pw[0 * 1152 + col * 72 + (th * 2 + kt) * 16 + grp * 4] = po;
        *(sh4*)&pw[1 * 1152 + col * 72 + (th * 2 + kt) * 16 + grp * 4] = pc;
      }
      // PV t-slice th: A-fragment k = grp*8 + th*32 + e covers keys [th*32, th*32+32)
#pragma unroll
      for (int h = 0; h < 2; ++h) {
        sh8 pa = *(const sh8*)&pw[h * 1152 + col * 72 + grp * 8 + th * 32];
#pragma unroll
        for (int dt = 0; dt < 4; ++dt) {
          const int drow = h * 64 + dt * 16 + col;
          sh8 bv = *(const sh8*)(vt + ((size_t)b * 128 + drow) * S_N + kc + grp * 8 + th * 32);
          acc[h][dt] = __builtin_amdgcn_mfma_f32_16x16x32_bf16(pa, bv, acc[h][dt], 0, 0, 0);
        }
      }
    }
  }

  // reduce sum-exp across the 4 lanes sharing q-col, stash per-wave
  rs0 += __shfl_xor(rs0, 16); rs0 += __shfl_xor(rs0, 32);
  rs1 += __shfl_xor(rs1, 16); rs1 += __shfl_xor(rs1, 32);
  if (lane < 16) {
    lsum_lds[wave][0][col] = rs0;
    lsum_lds[wave][1][col] = rs1;
  }
  // partial O -> per-wave LDS region [16][136] f32 (overlays P region)
  float* obuf = (float*)lds_raw[wave];
#pragma unroll
  for (int h = 0; h < 2; ++h)
#pragma unroll
    for (int dt = 0; dt < 4; ++dt)
#pragma unroll
      for (int r = 0; r < 4; ++r)
        obuf[(grp * 4 + r) * 136 + h * 64 + dt * 16 + col] = acc[h][dt][r];
  __syncthreads();

  // epilogue: 256 threads cover 16 rows x 128 dims
  const int orow = tid >> 4, d0 = (tid & 15) * 8;
  const float qm = qmask[(size_t)b * S_N + qbase + orow];
  float ls0 = lsum_lds[0][0][orow] + lsum_lds[1][0][orow] + lsum_lds[2][0][orow] + lsum_lds[3][0][orow];
  float ls1 = lsum_lds[0][1][orow] + lsum_lds[1][1][orow] + lsum_lds[2][1][orow] + lsum_lds[3][1][orow];
  f4 s0v = (f4)0.f, s1v = (f4)0.f;
#pragma unroll
  for (int w = 0; w < 4; ++w) {
    const float* ob = (const float*)lds_raw[w];
    s0v += *(const f4*)&ob[orow * 136 + d0];
    s1v += *(const f4*)&ob[orow * 136 + d0 + 4];
  }
  const float sc2 = qm / ((d0 >= 64) ? ls1 : ls0);
  const size_t o = ((size_t)(b * S_N + qbase + orow)) * 128 + d0;
  f4 q0 = *(const f4*)(qin + o), q1 = *(const f4*)(qin + o + 4);
  f4 r0v, r1v;
#pragma unroll
  for (int i = 0; i < 4; ++i) {
    r0v[i] = s0v[i] * sc2 + q0[i];
    r1v[i] = s1v[i] * sc2 + q1[i];
  }
  *(f4*)(out + o) = r0v;
  *(f4*)(out + o + 4) = r1v;
}

extern "C" void kernel_launch(void* const* d_in, const int* in_sizes, int n_in,
                              void* d_out, int out_size, void* d_ws, size_t ws_size,
                              hipStream_t stream) {
  const float* queries_it = (const float*)d_in[0];
  const float* queries_ctx = (const float*)d_in[1];
  const float* keys_it = (const float*)d_in[2];
  const float* keys_ctx = (const float*)d_in[3];
  const float* sigma = (const float*)d_in[4];
  const float* noise = (const float*)d_in[5];
  const float* Wq_it = (const float*)d_in[6];
  const float* bq_it = (const float*)d_in[7];
  const float* Wk_it = (const float*)d_in[8];
  const float* bk_it = (const float*)d_in[9];
  const float* Wq_ctx = (const float*)d_in[10];
  const float* bq_ctx = (const float*)d_in[11];
  const float* Wk_ctx = (const float*)d_in[12];
  const float* bk_ctx = (const float*)d_in[13];
  const float* Wv = (const float*)d_in[14];
  const float* bv = (const float*)d_in[15];
  const float* W1 = (const float*)d_in[16];
  const float* b1 = (const float*)d_in[17];
  const float* W2 = (const float*)d_in[18];
  const float* b2 = (const float*)d_in[19];
  float* out = (float*)d_out;

  char* ws = (char*)d_ws;
  short* qit = (short*)(ws);                    // 4 MB
  short* kit = (short*)(ws + (4ull << 20));     // 4 MB
  short* qctx = (short*)(ws + (8ull << 20));    // 4 MB
  short* kctx = (short*)(ws + (12ull << 20));   // 4 MB
  short* vt = (short*)(ws + (16ull << 20));     // 8 MB  [B,128,S]
  float* qmask = (float*)(ws + (24ull << 20));  // 128 KB
  float* kmask = (float*)(ws + (24ull << 20) + (size_t)B_N * S_N * 4);

  const int NR = B_N * S_N;
  proj_qk2<128><<<dim3(NR / 64), 256, 0, stream>>>(queries_it, Wq_it, bq_it, qit);
  proj_qk2<128><<<dim3(NR / 64), 256, 0, stream>>>(keys_it, Wk_it, bk_it, kit);
  proj_qk2<64><<<dim3(NR / 64), 256, 0, stream>>>(queries_ctx, Wq_ctx, bq_ctx, qctx);
  proj_qk2<64><<<dim3(NR / 64), 256, 0, stream>>>(keys_ctx, Wk_ctx, bk_ctx, kctx);
  proj_v2<<<dim3(NR / 64), 256, 0, stream>>>(keys_it, Wv, bv, vt);
  proj_v2<<<dim3(NR / 64), 256, 0, stream>>>(keys_it, Wv + 64 * 128, bv + 64, vt + 64ull * S_N);
  mask_kernel<<<dim3(NR / 256), 256, 0, stream>>>(queries_it, keys_it, qmask, kmask, NR);

  attn_kernel<<<dim3(B_N * (S_N / 16)), 256, 0, stream>>>(
      qit, kit, qctx, kctx, vt, noise, sigma, qmask, kmask, queries_it,
      W1, b1, W2, b2, out);
}